// Round 4
// baseline (267.082 us; speedup 1.0000x reference)
//
#include <hip/hip_runtime.h>
#include <hip/hip_bf16.h>
#include <math.h>

typedef __bf16 bf16_t;
typedef __bf16 bf16x8 __attribute__((ext_vector_type(8)));
typedef float floatx4 __attribute__((ext_vector_type(4)));

#define S_LEN 4096
#define DMODEL 1024
#define NH 16
#define DK 64
#define WELEM (DMODEL * DMODEL)
// 0.125 (1/sqrt(dk)) * log2(e): folded into RoPE's Q output (r13-validated)
#define SCALE_LOG2E 0.1803368801111204f
#define KPITCH 68   // attn P pitch: zero conflicts (r7-r15)

// qkv GEMM tile: 128x128, BK=64, pitch 72 (bank stride 36 -> worst 2-way, free)
#define QBM 128
#define QBN 128
#define QBK 64
#define QPITCH 72
// gemm_out tile (r10-validated): 128x64, BK=32, pitch 40
#define BM 128
#define BN 64
#define BK 32
#define APITCH 40

static __device__ __forceinline__ floatx4 mfma16(bf16x8 a, bf16x8 b, floatx4 c) {
  return __builtin_amdgcn_mfma_f32_16x16x32_bf16(a, b, c, 0, 0, 0);
}

// Raw barrier with lgkm-only wait: NO vmcnt drain (prefetch loads stay in
// flight across it — T3/T4). sched_barrier(0) pins scheduling on both sides
// (m201 discipline, rule #18).
static __device__ __forceinline__ void barrier_lgkm() {
  __builtin_amdgcn_sched_barrier(0);
  __asm__ volatile("s_waitcnt lgkmcnt(0)" ::: "memory");
  __builtin_amdgcn_s_barrier();
  __builtin_amdgcn_sched_barrier(0);
}

// fp32 -> bf16 elementwise convert (n multiple of 8).
__global__ __launch_bounds__(256) void cvt_f32_bf16(const float* __restrict__ src,
                                                    bf16_t* __restrict__ dst, int n) {
  int i = (blockIdx.x * blockDim.x + threadIdx.x) * 8;
  if (i >= n) return;
  float4 a = *(const float4*)(src + i);
  float4 b = *(const float4*)(src + i + 4);
  bf16x8 v;
  v[0] = (bf16_t)a.x; v[1] = (bf16_t)a.y; v[2] = (bf16_t)a.z; v[3] = (bf16_t)a.w;
  v[4] = (bf16_t)b.x; v[5] = (bf16_t)b.y; v[6] = (bf16_t)b.z; v[7] = (bf16_t)b.w;
  *(bf16x8*)(dst + i) = v;
}

// Convert Wq/Wk/Wv (fp32, 1M elems each) -> bf16 at dst[sel*WELEM].
__global__ __launch_bounds__(256) void wcvt3(const float* __restrict__ Wq,
                                             const float* __restrict__ Wk,
                                             const float* __restrict__ Wv,
                                             bf16_t* __restrict__ dst) {
  const int sel = blockIdx.y;
  const float* src = (sel == 0) ? Wq : ((sel == 1) ? Wk : Wv);
  int i = (blockIdx.x * blockDim.x + threadIdx.x) * 8;
  float4 a = *(const float4*)(src + i);
  float4 b = *(const float4*)(src + i + 4);
  bf16x8 v;
  v[0] = (bf16_t)a.x; v[1] = (bf16_t)a.y; v[2] = (bf16_t)a.z; v[3] = (bf16_t)a.w;
  v[4] = (bf16_t)b.x; v[5] = (bf16_t)b.y; v[6] = (bf16_t)b.z; v[7] = (bf16_t)b.w;
  *(bf16x8*)(dst + (size_t)sel * WELEM + i) = v;
}

// FUSED QKV GEMM, all-bf16: 128x128 tile, BK=64. Weights pre-converted (WB =
// [WqB|WkB|WvB] in d_out scratch). blockIdx.x: sel = x>>3, ntile = x&7.
// 4 waves (2x2), wave tile 64x64 (16 acc frags). Register-prefetch K-loop.
__global__ __launch_bounds__(256) void qkv_gemm(const bf16_t* __restrict__ A,
                                                const bf16_t* __restrict__ WB,
                                                bf16_t* __restrict__ Qo,
                                                bf16_t* __restrict__ Ko,
                                                bf16_t* __restrict__ Vo) {
  __shared__ __align__(16) bf16_t As[QBM * QPITCH];  // 18 KB
  __shared__ __align__(16) bf16_t Bs[QBN * QPITCH];  // 18 KB

  const int tid  = threadIdx.x;
  const int wid  = tid >> 6;
  const int lane = tid & 63;
  const int lr   = lane & 15;
  const int quad = lane >> 4;
  const int wm = wid >> 1, wn = wid & 1;
  const int sel = blockIdx.x >> 3;              // 0=Q, 1=K, 2=V
  const int n0  = (blockIdx.x & 7) * QBN;
  const int m0  = blockIdx.y * QBM;
  const bf16_t* Bsrc = WB + (size_t)sel * WELEM;

  // Staging: thread t -> row t>>1, k-offset (t&1)*32 (64 B = 4x bf16x8)
  const int sr = tid >> 1, sk = (tid & 1) * 32;
  const bf16_t* ag = A    + (size_t)(m0 + sr) * DMODEL + sk;
  const bf16_t* bg = Bsrc + (size_t)(n0 + sr) * DMODEL + sk;

  floatx4 acc[4][4];
#pragma unroll
  for (int i = 0; i < 4; ++i)
#pragma unroll
    for (int j = 0; j < 4; ++j) acc[i][j] = floatx4{0.f, 0.f, 0.f, 0.f};

  bf16x8 pa[4], pb[4];
#pragma unroll
  for (int u = 0; u < 4; ++u) {
    pa[u] = *(const bf16x8*)(ag + u * 8);
    pb[u] = *(const bf16x8*)(bg + u * 8);
  }

  for (int kb = 0; kb < DMODEL; kb += QBK) {
    __syncthreads();
#pragma unroll
    for (int u = 0; u < 4; ++u) {
      *(bf16x8*)(As + sr * QPITCH + sk + u * 8) = pa[u];
      *(bf16x8*)(Bs + sr * QPITCH + sk + u * 8) = pb[u];
    }
    __syncthreads();

    if (kb + QBK < DMODEL) {
#pragma unroll
      for (int u = 0; u < 4; ++u) {
        pa[u] = *(const bf16x8*)(ag + kb + QBK + u * 8);
        pb[u] = *(const bf16x8*)(bg + kb + QBK + u * 8);
      }
    }

#pragma unroll
    for (int s = 0; s < 2; ++s) {
      bf16x8 af[4], bfr[4];
#pragma unroll
      for (int i = 0; i < 4; ++i)
        af[i] = *(const bf16x8*)(As + (wm * 64 + i * 16 + lr) * QPITCH + s * 32 + quad * 8);
#pragma unroll
      for (int j = 0; j < 4; ++j)
        bfr[j] = *(const bf16x8*)(Bs + (wn * 64 + j * 16 + lr) * QPITCH + s * 32 + quad * 8);
#pragma unroll
      for (int i = 0; i < 4; ++i)
#pragma unroll
        for (int j = 0; j < 4; ++j)
          acc[i][j] = mfma16(af[i], bfr[j], acc[i][j]);
    }
  }

  bf16_t* Cn = (sel == 0) ? Qo : Ko;
#pragma unroll
  for (int i = 0; i < 4; ++i)
#pragma unroll
    for (int j = 0; j < 4; ++j)
#pragma unroll
      for (int r = 0; r < 4; ++r) {
        int row = m0 + wm * 64 + i * 16 + quad * 4 + r;
        int col = n0 + wn * 64 + j * 16 + lr;
        bf16_t v = (bf16_t)acc[i][j][r];
        if (sel < 2)
          Cn[(size_t)row * DMODEL + col] = v;
        else
          Vo[(size_t)col * S_LEN + row] = v;
      }
}

// Final GEMM: C(fp32) = A(bf16) @ WoB(bf16)^T. r10-validated 128x64/BK=32.
__global__ __launch_bounds__(256) void gemm_out(const bf16_t* __restrict__ A,
                                                const bf16_t* __restrict__ B,
                                                float* __restrict__ C,
                                                int M, int N, int Kd) {
  __shared__ __align__(16) bf16_t As[BM * APITCH];
  __shared__ __align__(16) bf16_t Bs[BN * APITCH];

  const int tid  = threadIdx.x;
  const int wid  = tid >> 6;
  const int lane = tid & 63;
  const int lr   = lane & 15;
  const int quad = lane >> 4;
  const int wm = wid >> 1, wn = wid & 1;
  const int m0 = blockIdx.y * BM;
  const int n0 = blockIdx.x * BN;

  const int ar = tid >> 1, ak = (tid & 1) * 16;
  const bf16_t* ag = A + (size_t)(m0 + ar) * Kd + ak;
  const int br = tid >> 2, bk = (tid & 3) * 8;
  const bf16_t* bg = B + (size_t)(n0 + br) * Kd + bk;

  floatx4 acc[4][2];
#pragma unroll
  for (int i = 0; i < 4; ++i)
#pragma unroll
    for (int j = 0; j < 2; ++j) acc[i][j] = floatx4{0.f, 0.f, 0.f, 0.f};

  bf16x8 pa0 = *(const bf16x8*)(ag);
  bf16x8 pa1 = *(const bf16x8*)(ag + 8);
  bf16x8 pb  = *(const bf16x8*)(bg);

  for (int kb = 0; kb < Kd; kb += BK) {
    __syncthreads();
    *(bf16x8*)(As + ar * APITCH + ak)     = pa0;
    *(bf16x8*)(As + ar * APITCH + ak + 8) = pa1;
    *(bf16x8*)(Bs + br * APITCH + bk)     = pb;
    __syncthreads();

    if (kb + BK < Kd) {
      pa0 = *(const bf16x8*)(ag + kb + BK);
      pa1 = *(const bf16x8*)(ag + kb + BK + 8);
      pb  = *(const bf16x8*)(bg + kb + BK);
    }

    bf16x8 af[4], bfr[2];
#pragma unroll
    for (int i = 0; i < 4; ++i)
      af[i] = *(const bf16x8*)(As + (wm * 64 + i * 16 + lr) * APITCH + quad * 8);
#pragma unroll
    for (int j = 0; j < 2; ++j)
      bfr[j] = *(const bf16x8*)(Bs + (wn * 32 + j * 16 + lr) * APITCH + quad * 8);

#pragma unroll
    for (int i = 0; i < 4; ++i)
#pragma unroll
      for (int j = 0; j < 2; ++j)
        acc[i][j] = mfma16(af[i], bfr[j], acc[i][j]);
  }

#pragma unroll
  for (int i = 0; i < 4; ++i)
#pragma unroll
    for (int j = 0; j < 2; ++j)
#pragma unroll
      for (int r = 0; r < 4; ++r) {
        int row = m0 + wm * 64 + i * 16 + quad * 4 + r;
        int col = n0 + wn * 32 + j * 16 + lr;
        C[(size_t)row * N + col] = acc[i][j][r];
      }
}

// In-place RoPE on Q and K. Q output pre-scaled by SCALE_LOG2E (r13-validated).
__global__ __launch_bounds__(256) void rope_kernel(bf16_t* __restrict__ Q,
                                                   bf16_t* __restrict__ K,
                                                   const void* __restrict__ posv) {
  int idx = blockIdx.x * blockDim.x + threadIdx.x;
  if (idx >= S_LEN * 512) return;
  int s   = idx >> 9;
  int rem = idx & 511;
  int h   = rem >> 5;
  int j   = rem & 31;
  size_t off = (size_t)s * DMODEL + h * DK + 2 * j;

  const long long* p64 = (const long long*)posv;
  const int*       p32 = (const int*)posv;
  unsigned long long w0 = (unsigned long long)p64[0];
  unsigned long long w1 = (unsigned long long)p64[1];
  bool is64 = ((w0 >> 32) == 0ull) && ((w1 >> 32) == 0ull);
  int safe_idx = is64 ? s : 0;
  long long v64 = p64[safe_idx];
  float p = is64 ? (float)v64 : (float)p32[s];

  float inv_freq = expf(-(float)j * (9.210340371976184f / 32.0f));
  float ang = p * inv_freq;
  float sn, cs;
  sincosf(ang, &sn, &cs);

  float q1 = (float)Q[off], q2 = (float)Q[off + 1];
  float csq = cs * SCALE_LOG2E, snq = sn * SCALE_LOG2E;
  Q[off]     = (bf16_t)(q1 * csq - q2 * snq);
  Q[off + 1] = (bf16_t)(q1 * snq + q2 * csq);

  float k1 = (float)K[off], k2 = (float)K[off + 1];
  K[off]     = (bf16_t)(k1 * cs - k2 * sn);
  K[off + 1] = (bf16_t)(k1 * sn + k2 * cs);
}

// Flash attention, r20: 4-way q-split (16 rows/wave), each wave computes BOTH
// ring chunks per iteration (ILP doubling — TLP is capped at 2 waves/SIMD by
// problem size, so latency hiding must come from in-wave overlap).
//   - block = 64 q-rows (tile p), wave w owns rows p*64+w*16 .. +15 across
//     ALL kv chunks -> direct O writes, NO cross-wave reduction epilogue.
//   - per iteration: stage chunks 2i, 2i+1 into the 2-slot ring (as r19),
//     then pipeline: {QK+exp2+P-write chunk0, chunk1} -> ONE lgkm drain ->
//     {P-read+V-read+PV chunk0, chunk1}. Chunk1's K-reads/MFMA overlap
//     chunk0's exp2/P-write latency; one drain/iter instead of two.
//   - lsum reduces lane-locally (shfl over lr lanes); PV output rows are
//     quad*4+r which matches the reduced lsum's lane ownership exactly.
//   - raw lgkm-only barriers (T3/T4) + setprio (T5) kept from r19.
__global__ __launch_bounds__(256, 2) void attn_kernel(const bf16_t* __restrict__ Q,
                                                      const bf16_t* __restrict__ Kb,
                                                      const bf16_t* __restrict__ Vt,
                                                      bf16_t* __restrict__ O) {
  // [0,16384): slot0 {K 8K | V 8K}, [16384,32768): slot1
  // [32768,50176): P: 8 groups (wid,chunk) x 16 rows x KPITCH u16
  __shared__ __align__(16) unsigned char smem[50176];

  const int tid  = threadIdx.x;
  const int wid  = tid >> 6;
  const int lane = tid & 63;
  const int lr   = lane & 15;
  const int quad = lane >> 4;

  const int bid = blockIdx.x;
  const int h   = bid & 15;
  const int pid = bid >> 4;    // 0..31

  const bf16_t* Kh = Kb + h * DK;
  const bf16_t* Vh = Vt + (size_t)h * DK * S_LEN;

  // P groups: (wid*2 + chunk) -> 16 x KPITCH u16
  unsigned short* Pg[2];
  Pg[0] = (unsigned short*)(smem + 32768) + (wid * 2 + 0) * 16 * KPITCH;
  Pg[1] = (unsigned short*)(smem + 32768) + (wid * 2 + 1) * 16 * KPITCH;

  // Staging geometry: thread t covers bytes [(t&7)*16, +16) of rows t>>3 and
  // (t>>3)+32 of each 64x128B chunk image. 8 fully-used lines per wave-instr.
  const int r0  = tid >> 3;                 // 0..31
  const int ke  = (tid & 7) * 8;            // element offset in row
  const int ls0 = (r0 * 128 + (tid & 7) * 16) ^ ((r0 & 7) << 4);
  const int ls1 = ls0 + 4096;               // row r0+32 (same &7 -> same swz)
  const int sw  = (lr & 7) << 4;            // frag-read swizzle

  bf16x8 kr[2][2], vr[2][2];

  // prologue: phase0 tile (63-pid), chunks {0,1} (maxc >= 33, both valid)
#pragma unroll
  for (int j = 0; j < 2; ++j) {
    const bf16_t* kg = Kh + (size_t)(j * 64 + r0) * DMODEL + ke;
    const bf16_t* vg = Vh + (size_t)r0 * S_LEN + j * 64 + ke;
    kr[j][0] = *(const bf16x8*)(kg);
    kr[j][1] = *(const bf16x8*)(kg + (size_t)32 * DMODEL);
    vr[j][0] = *(const bf16x8*)(vg);
    vr[j][1] = *(const bf16x8*)(vg + (size_t)32 * S_LEN);
  }

  for (int ph = 0; ph < 2; ++ph) {
    const int p    = ph ? pid : (63 - pid);
    const int maxc = p + 1;
    const int nit  = (maxc + 1) >> 1;
    const int q0   = p * 64 + wid * 16;   // this wave's 16 rows

    // Q fragments: lane holds Q[q0+lr][quad*8..] (A-operand layout)
    bf16x8 qf0, qf1;
    {
      const bf16_t* Qp = Q + (size_t)(q0 + lr) * DMODEL + h * DK + quad * 8;
      qf0 = *(const bf16x8*)(Qp);
      qf1 = *(const bf16x8*)(Qp + 32);
    }

    floatx4 o[4];
#pragma unroll
    for (int dt = 0; dt < 4; ++dt) o[dt] = floatx4{0.f, 0.f, 0.f, 0.f};
    float lsum[4] = {0.f, 0.f, 0.f, 0.f};

    for (int i = 0; i < nit; ++i) {
      barrier_lgkm();   // A: ring slots free (no vmcnt drain)
#pragma unroll
      for (int j = 0; j < 2; ++j) {
        unsigned char* Kd = smem + j * 16384;
        *(bf16x8*)(Kd + ls0)        = kr[j][0];
        *(bf16x8*)(Kd + ls1)        = kr[j][1];
        *(bf16x8*)(Kd + 8192 + ls0) = vr[j][0];
        *(bf16x8*)(Kd + 8192 + ls1) = vr[j][1];
      }
      {  // issue next-pair loads; stay in flight across barrier B, land
         // under this iteration's compute (reg-dep wait at next ds_write).
        int cn0 = 2 * i + 2; if (cn0 > maxc - 1) cn0 = maxc - 1;
        int cn1 = 2 * i + 3; if (cn1 > maxc - 1) cn1 = maxc - 1;
        const int cs0[2] = {cn0, cn1};
#pragma unroll
        for (int j = 0; j < 2; ++j) {
          const bf16_t* kg = Kh + (size_t)(cs0[j] * 64 + r0) * DMODEL + ke;
          const bf16_t* vg = Vh + (size_t)r0 * S_LEN + cs0[j] * 64 + ke;
          kr[j][0] = *(const bf16x8*)(kg);
          kr[j][1] = *(const bf16x8*)(kg + (size_t)32 * DMODEL);
          vr[j][0] = *(const bf16x8*)(vg);
          vr[j][1] = *(const bf16x8*)(vg + (size_t)32 * S_LEN);
        }
      }
      barrier_lgkm();   // B: ring staged (lgkm only; vmcnt in flight)

      // ---- pipeline stage 1: QK + softmax-numerator + P-write, both chunks
#pragma unroll
      for (int j = 0; j < 2; ++j) {
        const int c = 2 * i + j;
        if (c < maxc) {
          const int kvb = c * 64;
          const bool masked = (c == maxc - 1);
          unsigned char* Kbuf = smem + j * 16384;

          bf16x8 kf[4][2];
#pragma unroll
          for (int f = 0; f < 4; ++f) {
            const int rowb = (f * 16 + lr) * 128;
            kf[f][0] = *(const bf16x8*)(Kbuf + rowb + ((quad * 16) ^ sw));
            kf[f][1] = *(const bf16x8*)(Kbuf + rowb + ((quad * 16 + 64) ^ sw));
          }

          floatx4 s[4];
          __builtin_amdgcn_s_setprio(1);
#pragma unroll
          for (int f = 0; f < 4; ++f) {
            floatx4 z = {0.f, 0.f, 0.f, 0.f};
            z = mfma16(qf0, kf[f][0], z);
            s[f] = mfma16(qf1, kf[f][1], z);
          }
          __builtin_amdgcn_s_setprio(0);

#pragma unroll
          for (int f = 0; f < 4; ++f) {
#pragma unroll
            for (int r = 0; r < 4; ++r) {
              float pe = __builtin_amdgcn_exp2f(s[f][r]);
              if (masked) {
                int kv   = kvb + f * 16 + lr;
                int qrow = q0 + quad * 4 + r;
                pe = (kv <= qrow) ? pe : 0.f;
              }
              lsum[r] += pe;
              Pg[j][(quad * 4 + r) * KPITCH + f * 16 + lr] =
                  (unsigned short)(__float_as_uint(pe) >> 16);
            }
          }
        }
      }

      __asm__ volatile("s_waitcnt lgkmcnt(0)" ::: "memory");  // one drain/iter

      // ---- pipeline stage 2: P-read + V-read + PV, both chunks
#pragma unroll
      for (int j = 0; j < 2; ++j) {
        const int c = 2 * i + j;
        if (c < maxc) {
          unsigned char* Vbuf = smem + j * 16384 + 8192;
          const bf16_t* Pw = (const bf16_t*)Pg[j];

          bf16x8 pf0 = *(const bf16x8*)(Pw + lr * KPITCH + quad * 8);
          bf16x8 pf1 = *(const bf16x8*)(Pw + lr * KPITCH + 32 + quad * 8);

          __builtin_amdgcn_s_setprio(1);
#pragma unroll
          for (int dt = 0; dt < 4; ++dt) {
            const int rowb = (dt * 16 + lr) * 128;
            bf16x8 v0 = *(const bf16x8*)(Vbuf + rowb + ((quad * 16) ^ sw));
            bf16x8 v1 = *(const bf16x8*)(Vbuf + rowb + ((quad * 16 + 64) ^ sw));
            o[dt] = mfma16(pf0, v0, o[dt]);
            o[dt] = mfma16(pf1, v1, o[dt]);
          }
          __builtin_amdgcn_s_setprio(0);
        }
      }
    }

    // prefetch next phase's chunks {0, min(1,pid)}; lands under epilogue
    if (ph == 0) {
      const int c1 = (pid >= 1) ? 1 : 0;
      const int cs1[2] = {0, c1};
#pragma unroll
      for (int j = 0; j < 2; ++j) {
        const bf16_t* kg = Kh + (size_t)(cs1[j] * 64 + r0) * DMODEL + ke;
        const bf16_t* vg = Vh + (size_t)r0 * S_LEN + cs1[j] * 64 + ke;
        kr[j][0] = *(const bf16x8*)(kg);
        kr[j][1] = *(const bf16x8*)(kg + (size_t)32 * DMODEL);
        vr[j][0] = *(const bf16x8*)(vg);
        vr[j][1] = *(const bf16x8*)(vg + (size_t)32 * S_LEN);
      }
    }

    // lane-reduce lsum across the 16 kv lanes (lr). After this, lane
    // (lr,quad) holds lsum for rows q0+quad*4+r — exactly its PV output rows.
#pragma unroll
    for (int m = 1; m < 16; m <<= 1) {
#pragma unroll
      for (int r = 0; r < 4; ++r) lsum[r] += __shfl_xor(lsum[r], m, 64);
    }
    float inv[4];
#pragma unroll
    for (int r = 0; r < 4; ++r) inv[r] = 1.0f / lsum[r];

    // direct O write: wave owns rows q0..q0+15 completely
#pragma unroll
    for (int dt = 0; dt < 4; ++dt)
#pragma unroll
      for (int r = 0; r < 4; ++r) {
        int row = q0 + quad * 4 + r;
        O[(size_t)row * DMODEL + h * DK + dt * 16 + lr] =
            (bf16_t)(o[dt][r] * inv[r]);
      }
    // next phase's barrier A orders ring reuse after this phase's LDS reads
  }
}

extern "C" void kernel_launch(void* const* d_in, const int* in_sizes, int n_in,
                              void* d_out, int out_size, void* d_ws, size_t ws_size,
                              hipStream_t stream) {
  const float* x  = (const float*)d_in[0];
  const float* Wq = (const float*)d_in[1];
  const float* Wk = (const float*)d_in[2];
  const float* Wv = (const float*)d_in[3];
  const float* Wo = (const float*)d_in[4];
  const void* pos = d_in[5];
  float* out = (float*)d_out;

  const size_t NELEM = (size_t)S_LEN * DMODEL;  // 4M elems

  // ws: 32 MB. d_out doubles as bf16 weight scratch until gemm_out.
  bf16_t* xb  = (bf16_t*)d_ws;   // 8 MB (later Ob)
  bf16_t* Qb  = xb + NELEM;      // 8 MB (later WoB)
  bf16_t* Kb  = Qb + NELEM;      // 8 MB
  bf16_t* Vt  = Kb + NELEM;      // 8 MB
  bf16_t* Ob  = xb;
  bf16_t* WB  = (bf16_t*)d_out;  // [WqB|WkB|WvB] bf16, 6 MB of the 16 MB buffer
  bf16_t* WoB = Qb;              // Wo bf16 in Qb region (free after attn)

  dim3 blk(256);

  wcvt3<<<dim3(WELEM / 2048, 3), blk, 0, stream>>>(Wq, Wk, Wv, WB);
  cvt_f32_bf16<<<(int)(NELEM / 8 / 256), blk, 0, stream>>>(x, xb, (int)NELEM);

  // 24 x 32 = 768 blocks (3/CU)
  dim3 gq(3 * DMODEL / QBN, S_LEN / QBM);
  qkv_gemm<<<gq, blk, 0, stream>>>(xb, WB, Qb, Kb, Vt);

  int npairs = S_LEN * 512;
  rope_kernel<<<(npairs + 255) / 256, blk, 0, stream>>>(Qb, Kb, pos);

  // 16 h x 32 pairs (tiles 63-pid then pid), 512 uniform blocks, 2/CU
  attn_kernel<<<NH * 32, blk, 0, stream>>>(Qb, Kb, Vt, Ob);

  wcvt3<<<dim3(WELEM / 2048, 1), blk, 0, stream>>>(Wo, Wo, Wo, WoB);

  dim3 gg(DMODEL / BN, S_LEN / BM);  // (16, 32)
  gemm_out<<<gg, blk, 0, stream>>>(Ob, WoB, out, S_LEN, DMODEL, DMODEL);
}

// Round 5
// 231.155 us; speedup vs baseline: 1.1554x; 1.1554x over previous
//
#include <hip/hip_runtime.h>
#include <hip/hip_bf16.h>
#include <math.h>

typedef __bf16 bf16_t;
typedef __bf16 bf16x8 __attribute__((ext_vector_type(8)));
typedef float floatx4 __attribute__((ext_vector_type(4)));
typedef unsigned int uintx4 __attribute__((ext_vector_type(4)));

#define S_LEN 4096
#define DMODEL 1024
#define NH 16
#define DK 64
#define WELEM (DMODEL * DMODEL)
// 0.125 (1/sqrt(dk)) * log2(e): folded into RoPE's Q output (r13-validated)
#define SCALE_LOG2E 0.1803368801111204f

// qkv GEMM tile: 128x128, BK=64, pitch 72 (bank stride 36 -> worst 2-way, free)
#define QBM 128
#define QBN 128
#define QBK 64
#define QPITCH 72
// gemm_out tile (r10-validated): 128x64, BK=32, pitch 40
#define BM 128
#define BN 64
#define BK 32
#define APITCH 40

static __device__ __forceinline__ floatx4 mfma16(bf16x8 a, bf16x8 b, floatx4 c) {
  return __builtin_amdgcn_mfma_f32_16x16x32_bf16(a, b, c, 0, 0, 0);
}

// Raw barrier with lgkm-only wait: NO vmcnt drain (prefetch loads stay in
// flight across it — T3/T4). sched_barrier(0) pins scheduling on both sides.
static __device__ __forceinline__ void barrier_lgkm() {
  __builtin_amdgcn_sched_barrier(0);
  __asm__ volatile("s_waitcnt lgkmcnt(0)" ::: "memory");
  __builtin_amdgcn_s_barrier();
  __builtin_amdgcn_sched_barrier(0);
}

// bf16 pair pack (truncation — same rounding as the validated >>16 path):
// low half = a, high half = b.
static __device__ __forceinline__ unsigned int packbf(float a, float b) {
  return (__float_as_uint(a) >> 16) | (__float_as_uint(b) & 0xffff0000u);
}

// Paired cross-quad word exchanges (gfx950 permlane*_swap).
// swap32: a@{q2,q3} <-> b@{q0,q1}.  swap16: a@q1<->b@q0, a@q3<->b@q2.
static __device__ __forceinline__ void swap32(unsigned int& a, unsigned int& b) {
  auto r = __builtin_amdgcn_permlane32_swap(a, b, false, false);
  a = r[0]; b = r[1];
}
static __device__ __forceinline__ void swap16(unsigned int& a, unsigned int& b) {
  auto r = __builtin_amdgcn_permlane16_swap(a, b, false, false);
  a = r[0]; b = r[1];
}

// fp32 -> bf16 elementwise convert (n multiple of 8).
__global__ __launch_bounds__(256) void cvt_f32_bf16(const float* __restrict__ src,
                                                    bf16_t* __restrict__ dst, int n) {
  int i = (blockIdx.x * blockDim.x + threadIdx.x) * 8;
  if (i >= n) return;
  float4 a = *(const float4*)(src + i);
  float4 b = *(const float4*)(src + i + 4);
  bf16x8 v;
  v[0] = (bf16_t)a.x; v[1] = (bf16_t)a.y; v[2] = (bf16_t)a.z; v[3] = (bf16_t)a.w;
  v[4] = (bf16_t)b.x; v[5] = (bf16_t)b.y; v[6] = (bf16_t)b.z; v[7] = (bf16_t)b.w;
  *(bf16x8*)(dst + i) = v;
}

// Convert Wq/Wk/Wv (fp32, 1M elems each) -> bf16 at dst[sel*WELEM].
__global__ __launch_bounds__(256) void wcvt3(const float* __restrict__ Wq,
                                             const float* __restrict__ Wk,
                                             const float* __restrict__ Wv,
                                             bf16_t* __restrict__ dst) {
  const int sel = blockIdx.y;
  const float* src = (sel == 0) ? Wq : ((sel == 1) ? Wk : Wv);
  int i = (blockIdx.x * blockDim.x + threadIdx.x) * 8;
  float4 a = *(const float4*)(src + i);
  float4 b = *(const float4*)(src + i + 4);
  bf16x8 v;
  v[0] = (bf16_t)a.x; v[1] = (bf16_t)a.y; v[2] = (bf16_t)a.z; v[3] = (bf16_t)a.w;
  v[4] = (bf16_t)b.x; v[5] = (bf16_t)b.y; v[6] = (bf16_t)b.z; v[7] = (bf16_t)b.w;
  *(bf16x8*)(dst + (size_t)sel * WELEM + i) = v;
}

// FUSED QKV GEMM, all-bf16: 128x128 tile, BK=64. Weights pre-converted (WB =
// [WqB|WkB|WvB] in d_out scratch). blockIdx.x: sel = x>>3, ntile = x&7.
// 4 waves (2x2), wave tile 64x64 (16 acc frags). Register-prefetch K-loop.
__global__ __launch_bounds__(256) void qkv_gemm(const bf16_t* __restrict__ A,
                                                const bf16_t* __restrict__ WB,
                                                bf16_t* __restrict__ Qo,
                                                bf16_t* __restrict__ Ko,
                                                bf16_t* __restrict__ Vo) {
  __shared__ __align__(16) bf16_t As[QBM * QPITCH];  // 18 KB
  __shared__ __align__(16) bf16_t Bs[QBN * QPITCH];  // 18 KB

  const int tid  = threadIdx.x;
  const int wid  = tid >> 6;
  const int lane = tid & 63;
  const int lr   = lane & 15;
  const int quad = lane >> 4;
  const int wm = wid >> 1, wn = wid & 1;
  const int sel = blockIdx.x >> 3;              // 0=Q, 1=K, 2=V
  const int n0  = (blockIdx.x & 7) * QBN;
  const int m0  = blockIdx.y * QBM;
  const bf16_t* Bsrc = WB + (size_t)sel * WELEM;

  // Staging: thread t -> row t>>1, k-offset (t&1)*32 (64 B = 4x bf16x8)
  const int sr = tid >> 1, sk = (tid & 1) * 32;
  const bf16_t* ag = A    + (size_t)(m0 + sr) * DMODEL + sk;
  const bf16_t* bg = Bsrc + (size_t)(n0 + sr) * DMODEL + sk;

  floatx4 acc[4][4];
#pragma unroll
  for (int i = 0; i < 4; ++i)
#pragma unroll
    for (int j = 0; j < 4; ++j) acc[i][j] = floatx4{0.f, 0.f, 0.f, 0.f};

  bf16x8 pa[4], pb[4];
#pragma unroll
  for (int u = 0; u < 4; ++u) {
    pa[u] = *(const bf16x8*)(ag + u * 8);
    pb[u] = *(const bf16x8*)(bg + u * 8);
  }

  for (int kb = 0; kb < DMODEL; kb += QBK) {
    __syncthreads();
#pragma unroll
    for (int u = 0; u < 4; ++u) {
      *(bf16x8*)(As + sr * QPITCH + sk + u * 8) = pa[u];
      *(bf16x8*)(Bs + sr * QPITCH + sk + u * 8) = pb[u];
    }
    __syncthreads();

    if (kb + QBK < DMODEL) {
#pragma unroll
      for (int u = 0; u < 4; ++u) {
        pa[u] = *(const bf16x8*)(ag + kb + QBK + u * 8);
        pb[u] = *(const bf16x8*)(bg + kb + QBK + u * 8);
      }
    }

#pragma unroll
    for (int s = 0; s < 2; ++s) {
      bf16x8 af[4], bfr[4];
#pragma unroll
      for (int i = 0; i < 4; ++i)
        af[i] = *(const bf16x8*)(As + (wm * 64 + i * 16 + lr) * QPITCH + s * 32 + quad * 8);
#pragma unroll
      for (int j = 0; j < 4; ++j)
        bfr[j] = *(const bf16x8*)(Bs + (wn * 64 + j * 16 + lr) * QPITCH + s * 32 + quad * 8);
#pragma unroll
      for (int i = 0; i < 4; ++i)
#pragma unroll
        for (int j = 0; j < 4; ++j)
          acc[i][j] = mfma16(af[i], bfr[j], acc[i][j]);
    }
  }

  bf16_t* Cn = (sel == 0) ? Qo : Ko;
#pragma unroll
  for (int i = 0; i < 4; ++i)
#pragma unroll
    for (int j = 0; j < 4; ++j)
#pragma unroll
      for (int r = 0; r < 4; ++r) {
        int row = m0 + wm * 64 + i * 16 + quad * 4 + r;
        int col = n0 + wn * 64 + j * 16 + lr;
        bf16_t v = (bf16_t)acc[i][j][r];
        if (sel < 2)
          Cn[(size_t)row * DMODEL + col] = v;
        else
          Vo[(size_t)col * S_LEN + row] = v;
      }
}

// Final GEMM: C(fp32) = A(bf16) @ WoB(bf16)^T. r10-validated 128x64/BK=32.
__global__ __launch_bounds__(256) void gemm_out(const bf16_t* __restrict__ A,
                                                const bf16_t* __restrict__ B,
                                                float* __restrict__ C,
                                                int M, int N, int Kd) {
  __shared__ __align__(16) bf16_t As[BM * APITCH];
  __shared__ __align__(16) bf16_t Bs[BN * APITCH];

  const int tid  = threadIdx.x;
  const int wid  = tid >> 6;
  const int lane = tid & 63;
  const int lr   = lane & 15;
  const int quad = lane >> 4;
  const int wm = wid >> 1, wn = wid & 1;
  const int m0 = blockIdx.y * BM;
  const int n0 = blockIdx.x * BN;

  const int ar = tid >> 1, ak = (tid & 1) * 16;
  const bf16_t* ag = A + (size_t)(m0 + ar) * Kd + ak;
  const int br = tid >> 2, bk = (tid & 3) * 8;
  const bf16_t* bg = B + (size_t)(n0 + br) * Kd + bk;

  floatx4 acc[4][2];
#pragma unroll
  for (int i = 0; i < 4; ++i)
#pragma unroll
    for (int j = 0; j < 2; ++j) acc[i][j] = floatx4{0.f, 0.f, 0.f, 0.f};

  bf16x8 pa0 = *(const bf16x8*)(ag);
  bf16x8 pa1 = *(const bf16x8*)(ag + 8);
  bf16x8 pb  = *(const bf16x8*)(bg);

  for (int kb = 0; kb < Kd; kb += BK) {
    __syncthreads();
    *(bf16x8*)(As + ar * APITCH + ak)     = pa0;
    *(bf16x8*)(As + ar * APITCH + ak + 8) = pa1;
    *(bf16x8*)(Bs + br * APITCH + bk)     = pb;
    __syncthreads();

    if (kb + BK < Kd) {
      pa0 = *(const bf16x8*)(ag + kb + BK);
      pa1 = *(const bf16x8*)(ag + kb + BK + 8);
      pb  = *(const bf16x8*)(bg + kb + BK);
    }

    bf16x8 af[4], bfr[2];
#pragma unroll
    for (int i = 0; i < 4; ++i)
      af[i] = *(const bf16x8*)(As + (wm * 64 + i * 16 + lr) * APITCH + quad * 8);
#pragma unroll
    for (int j = 0; j < 2; ++j)
      bfr[j] = *(const bf16x8*)(Bs + (wn * 32 + j * 16 + lr) * APITCH + quad * 8);

#pragma unroll
    for (int i = 0; i < 4; ++i)
#pragma unroll
      for (int j = 0; j < 2; ++j)
        acc[i][j] = mfma16(af[i], bfr[j], acc[i][j]);
  }

#pragma unroll
  for (int i = 0; i < 4; ++i)
#pragma unroll
    for (int j = 0; j < 2; ++j)
#pragma unroll
      for (int r = 0; r < 4; ++r) {
        int row = m0 + wm * 64 + i * 16 + quad * 4 + r;
        int col = n0 + wn * 32 + j * 16 + lr;
        C[(size_t)row * N + col] = acc[i][j][r];
      }
}

// In-place RoPE on Q and K. Q output pre-scaled by SCALE_LOG2E (r13-validated).
__global__ __launch_bounds__(256) void rope_kernel(bf16_t* __restrict__ Q,
                                                   bf16_t* __restrict__ K,
                                                   const void* __restrict__ posv) {
  int idx = blockIdx.x * blockDim.x + threadIdx.x;
  if (idx >= S_LEN * 512) return;
  int s   = idx >> 9;
  int rem = idx & 511;
  int h   = rem >> 5;
  int j   = rem & 31;
  size_t off = (size_t)s * DMODEL + h * DK + 2 * j;

  const long long* p64 = (const long long*)posv;
  const int*       p32 = (const int*)posv;
  unsigned long long w0 = (unsigned long long)p64[0];
  unsigned long long w1 = (unsigned long long)p64[1];
  bool is64 = ((w0 >> 32) == 0ull) && ((w1 >> 32) == 0ull);
  int safe_idx = is64 ? s : 0;
  long long v64 = p64[safe_idx];
  float p = is64 ? (float)v64 : (float)p32[s];

  float inv_freq = expf(-(float)j * (9.210340371976184f / 32.0f));
  float ang = p * inv_freq;
  float sn, cs;
  sincosf(ang, &sn, &cs);

  float q1 = (float)Q[off], q2 = (float)Q[off + 1];
  float csq = cs * SCALE_LOG2E, snq = sn * SCALE_LOG2E;
  Q[off]     = (bf16_t)(q1 * csq - q2 * snq);
  Q[off + 1] = (bf16_t)(q1 * snq + q2 * csq);

  float k1 = (float)K[off], k2 = (float)K[off + 1];
  K[off]     = (bf16_t)(k1 * cs - k2 * sn);
  K[off + 1] = (bf16_t)(k1 * sn + k2 * cs);
}

// Flash attention, r21: r20 structure + IN-REGISTER P transpose (T12 adapted
// to 16x16 fragments). The LDS pipe was the r18-r20 bottleneck (~98% busy:
// 910 DS-cycles/wave-iter, 42% of it the P round-trip: 64 ds_write_b16 +
// reads + a full lgkm drain). This round deletes that entirely:
//   - QK^T computed SWAPPED: sT = mfma(K, Q). Lane (lr,quad) then holds
//     P[q=lr][kv=f*16+quad*4+r] — the q-row is lane-local.
//   - pe pairs packed to u32 bf16 words; 4x4 cross-quad word transpose via
//     one permlane32_swap + one permlane16_swap per word pair (8 swaps +
//     8 packs per chunk, pure VALU). Derivation: pf word m for quad qt =
//     W[f=qt>>1][p=m&1] pulled from quad (qt&1)*2+(m>>1); after
//     swap32(X0,X1);swap16(X0,X1): X0 = that word exactly (verified).
//   - lsum is lane-local (all 16 pe of a chunk belong to q=lr): scalar
//     accumulate, shfl_xor(16|32) reduce at phase end, per-row inv via
//     __shfl(lsum, quad*4+r).
//   - No P LDS region (smem = 32KB), no mid-loop lgkm drain.
//   DS per wave-iter: 910 -> 480 cy (8 stage-writes + 16 K + 16 V b128).
__global__ __launch_bounds__(256, 2) void attn_kernel(const bf16_t* __restrict__ Q,
                                                      const bf16_t* __restrict__ Kb,
                                                      const bf16_t* __restrict__ Vt,
                                                      bf16_t* __restrict__ O) {
  // [0,16384): slot0 {K 8K | V 8K}, [16384,32768): slot1
  __shared__ __align__(16) unsigned char smem[32768];

  const int tid  = threadIdx.x;
  const int wid  = tid >> 6;
  const int lane = tid & 63;
  const int lr   = lane & 15;
  const int quad = lane >> 4;

  const int bid = blockIdx.x;
  const int h   = bid & 15;
  const int pid = bid >> 4;    // 0..31

  const bf16_t* Kh = Kb + h * DK;
  const bf16_t* Vh = Vt + (size_t)h * DK * S_LEN;

  // Staging geometry: thread t covers bytes [(t&7)*16, +16) of rows t>>3 and
  // (t>>3)+32 of each 64x128B chunk image. 8 fully-used lines per wave-instr.
  const int r0  = tid >> 3;                 // 0..31
  const int ke  = (tid & 7) * 8;            // element offset in row
  const int ls0 = (r0 * 128 + (tid & 7) * 16) ^ ((r0 & 7) << 4);
  const int ls1 = ls0 + 4096;               // row r0+32 (same &7 -> same swz)
  const int sw  = (lr & 7) << 4;            // frag-read swizzle

  bf16x8 kr[2][2], vr[2][2];

  // prologue: phase0 tile (63-pid), chunks {0,1} (maxc >= 33, both valid)
#pragma unroll
  for (int j = 0; j < 2; ++j) {
    const bf16_t* kg = Kh + (size_t)(j * 64 + r0) * DMODEL + ke;
    const bf16_t* vg = Vh + (size_t)r0 * S_LEN + j * 64 + ke;
    kr[j][0] = *(const bf16x8*)(kg);
    kr[j][1] = *(const bf16x8*)(kg + (size_t)32 * DMODEL);
    vr[j][0] = *(const bf16x8*)(vg);
    vr[j][1] = *(const bf16x8*)(vg + (size_t)32 * S_LEN);
  }

  for (int ph = 0; ph < 2; ++ph) {
    const int p    = ph ? pid : (63 - pid);
    const int maxc = p + 1;
    const int nit  = (maxc + 1) >> 1;
    const int q0   = p * 64 + wid * 16;   // this wave's 16 rows

    // Q fragments: lane holds Q[q0+lr][quad*8..] (B-operand layout for the
    // swapped QK, A-operand for nothing else — same load as r20)
    bf16x8 qf0, qf1;
    {
      const bf16_t* Qp = Q + (size_t)(q0 + lr) * DMODEL + h * DK + quad * 8;
      qf0 = *(const bf16x8*)(Qp);
      qf1 = *(const bf16x8*)(Qp + 32);
    }

    floatx4 o[4];
#pragma unroll
    for (int dt = 0; dt < 4; ++dt) o[dt] = floatx4{0.f, 0.f, 0.f, 0.f};
    float lsum = 0.f;

    for (int i = 0; i < nit; ++i) {
      barrier_lgkm();   // A: ring slots free (no vmcnt drain)
#pragma unroll
      for (int j = 0; j < 2; ++j) {
        unsigned char* Kd = smem + j * 16384;
        *(bf16x8*)(Kd + ls0)        = kr[j][0];
        *(bf16x8*)(Kd + ls1)        = kr[j][1];
        *(bf16x8*)(Kd + 8192 + ls0) = vr[j][0];
        *(bf16x8*)(Kd + 8192 + ls1) = vr[j][1];
      }
      {  // issue next-pair loads; stay in flight across barrier B, land
         // under this iteration's compute (reg-dep wait at next ds_write).
        int cn0 = 2 * i + 2; if (cn0 > maxc - 1) cn0 = maxc - 1;
        int cn1 = 2 * i + 3; if (cn1 > maxc - 1) cn1 = maxc - 1;
        const int cs0[2] = {cn0, cn1};
#pragma unroll
        for (int j = 0; j < 2; ++j) {
          const bf16_t* kg = Kh + (size_t)(cs0[j] * 64 + r0) * DMODEL + ke;
          const bf16_t* vg = Vh + (size_t)r0 * S_LEN + cs0[j] * 64 + ke;
          kr[j][0] = *(const bf16x8*)(kg);
          kr[j][1] = *(const bf16x8*)(kg + (size_t)32 * DMODEL);
          vr[j][0] = *(const bf16x8*)(vg);
          vr[j][1] = *(const bf16x8*)(vg + (size_t)32 * S_LEN);
        }
      }
      barrier_lgkm();   // B: ring staged (lgkm only; vmcnt in flight)

#pragma unroll
      for (int j = 0; j < 2; ++j) {
        const int c = 2 * i + j;
        if (c < maxc) {
          const int kvb = c * 64;
          const bool masked = (c == maxc - 1);
          unsigned char* Kbuf = smem + j * 16384;
          unsigned char* Vbuf = Kbuf + 8192;

          bf16x8 kf[4][2];
#pragma unroll
          for (int f = 0; f < 4; ++f) {
            const int rowb = (f * 16 + lr) * 128;
            kf[f][0] = *(const bf16x8*)(Kbuf + rowb + ((quad * 16) ^ sw));
            kf[f][1] = *(const bf16x8*)(Kbuf + rowb + ((quad * 16 + 64) ^ sw));
          }

          // SWAPPED QK: A=K (rows=kv), B=Q (cols=q). Lane (lr,quad) gets
          // S[q=q0+lr][kv=kvb+f*16+quad*4+r].
          floatx4 s[4];
          __builtin_amdgcn_s_setprio(1);
#pragma unroll
          for (int f = 0; f < 4; ++f) {
            floatx4 z = {0.f, 0.f, 0.f, 0.f};
            z = mfma16(kf[f][0], qf0, z);
            s[f] = mfma16(kf[f][1], qf1, z);
          }
          __builtin_amdgcn_s_setprio(0);

          // exp2 + causal mask + lane-local lsum; pack to bf16 pair words
          unsigned int w[4][2];
#pragma unroll
          for (int f = 0; f < 4; ++f) {
            float pe[4];
#pragma unroll
            for (int r = 0; r < 4; ++r) {
              float v = __builtin_amdgcn_exp2f(s[f][r]);
              if (masked) {
                int kv   = kvb + f * 16 + quad * 4 + r;
                int qrow = q0 + lr;
                v = (kv <= qrow) ? v : 0.f;
              }
              lsum += v;
              pe[r] = v;
            }
            w[f][0] = packbf(pe[0], pe[1]);
            w[f][1] = packbf(pe[2], pe[3]);
          }

          // 4x4 cross-quad word transpose -> PV A-operand fragments.
          swap32(w[0][0], w[1][0]); swap16(w[0][0], w[1][0]);
          swap32(w[0][1], w[1][1]); swap16(w[0][1], w[1][1]);
          swap32(w[2][0], w[3][0]); swap16(w[2][0], w[3][0]);
          swap32(w[2][1], w[3][1]); swap16(w[2][1], w[3][1]);
          uintx4 u0 = {w[0][0], w[0][1], w[1][0], w[1][1]};
          uintx4 u1 = {w[2][0], w[2][1], w[3][0], w[3][1]};
          bf16x8 pf0, pf1;
          __builtin_memcpy(&pf0, &u0, 16);
          __builtin_memcpy(&pf1, &u1, 16);

          __builtin_amdgcn_s_setprio(1);
#pragma unroll
          for (int dt = 0; dt < 4; ++dt) {
            const int rowb = (dt * 16 + lr) * 128;
            bf16x8 v0 = *(const bf16x8*)(Vbuf + rowb + ((quad * 16) ^ sw));
            bf16x8 v1 = *(const bf16x8*)(Vbuf + rowb + ((quad * 16 + 64) ^ sw));
            o[dt] = mfma16(pf0, v0, o[dt]);
            o[dt] = mfma16(pf1, v1, o[dt]);
          }
          __builtin_amdgcn_s_setprio(0);
        }
      }
    }

    // prefetch next phase's chunks {0, min(1,pid)}; lands under epilogue
    if (ph == 0) {
      const int c1 = (pid >= 1) ? 1 : 0;
      const int cs1[2] = {0, c1};
#pragma unroll
      for (int j = 0; j < 2; ++j) {
        const bf16_t* kg = Kh + (size_t)(cs1[j] * 64 + r0) * DMODEL + ke;
        const bf16_t* vg = Vh + (size_t)r0 * S_LEN + cs1[j] * 64 + ke;
        kr[j][0] = *(const bf16x8*)(kg);
        kr[j][1] = *(const bf16x8*)(kg + (size_t)32 * DMODEL);
        vr[j][0] = *(const bf16x8*)(vg);
        vr[j][1] = *(const bf16x8*)(vg + (size_t)32 * S_LEN);
      }
    }

    // lsum currently: lane (lr,quad) has partial for q=q0+lr over its quad's
    // kv slots. Reduce across quads -> every lane has total for q=q0+lr.
    lsum += __shfl_xor(lsum, 16, 64);
    lsum += __shfl_xor(lsum, 32, 64);

    // PV output rows are q0+quad*4+r; fetch that row's lsum from lane
    // (quad*4+r) (its lr == quad*4+r).
    float inv[4];
#pragma unroll
    for (int r = 0; r < 4; ++r) inv[r] = 1.0f / __shfl(lsum, quad * 4 + r, 64);

    // direct O write: wave owns rows q0..q0+15 completely
#pragma unroll
    for (int dt = 0; dt < 4; ++dt)
#pragma unroll
      for (int r = 0; r < 4; ++r) {
        int row = q0 + quad * 4 + r;
        O[(size_t)row * DMODEL + h * DK + dt * 16 + lr] =
            (bf16_t)(o[dt][r] * inv[r]);
      }
    // next phase's barrier A orders ring reuse after this phase's LDS reads
  }
}

extern "C" void kernel_launch(void* const* d_in, const int* in_sizes, int n_in,
                              void* d_out, int out_size, void* d_ws, size_t ws_size,
                              hipStream_t stream) {
  const float* x  = (const float*)d_in[0];
  const float* Wq = (const float*)d_in[1];
  const float* Wk = (const float*)d_in[2];
  const float* Wv = (const float*)d_in[3];
  const float* Wo = (const float*)d_in[4];
  const void* pos = d_in[5];
  float* out = (float*)d_out;

  const size_t NELEM = (size_t)S_LEN * DMODEL;  // 4M elems

  // ws: 32 MB. d_out doubles as bf16 weight scratch until gemm_out.
  bf16_t* xb  = (bf16_t*)d_ws;   // 8 MB (later Ob)
  bf16_t* Qb  = xb + NELEM;      // 8 MB (later WoB)
  bf16_t* Kb  = Qb + NELEM;      // 8 MB
  bf16_t* Vt  = Kb + NELEM;      // 8 MB
  bf16_t* Ob  = xb;
  bf16_t* WB  = (bf16_t*)d_out;  // [WqB|WkB|WvB] bf16, 6 MB of the 16 MB buffer
  bf16_t* WoB = Qb;              // Wo bf16 in Qb region (free after attn)

  dim3 blk(256);

  wcvt3<<<dim3(WELEM / 2048, 3), blk, 0, stream>>>(Wq, Wk, Wv, WB);
  cvt_f32_bf16<<<(int)(NELEM / 8 / 256), blk, 0, stream>>>(x, xb, (int)NELEM);

  // 24 x 32 = 768 blocks (3/CU)
  dim3 gq(3 * DMODEL / QBN, S_LEN / QBM);
  qkv_gemm<<<gq, blk, 0, stream>>>(xb, WB, Qb, Kb, Vt);

  int npairs = S_LEN * 512;
  rope_kernel<<<(npairs + 255) / 256, blk, 0, stream>>>(Qb, Kb, pos);

  // 16 h x 32 pairs (tiles 63-pid then pid), 512 uniform blocks, 2/CU
  attn_kernel<<<NH * 32, blk, 0, stream>>>(Qb, Kb, Vt, Ob);

  wcvt3<<<dim3(WELEM / 2048, 1), blk, 0, stream>>>(Wo, Wo, Wo, WoB);

  dim3 gg(DMODEL / BN, S_LEN / BM);  // (16, 32)
  gemm_out<<<gg, blk, 0, stream>>>(Ob, WoB, out, S_LEN, DMODEL, DMODEL);
}